// Round 4
// baseline (129.566 us; speedup 1.0000x reference)
//
#include <hip/hip_runtime.h>
#include <stdint.h>
#include <math.h>

// Problem geometry (fixed by the reference)
#define TT        256                       // T_STEPS
#define COLS      (16*8*1024*2)             // N*C*Do*Di = 262144
#define CS4       (COLS/4)                  // 65536
#define DMASK     (1024*2 - 1)              // Do*Di-1 (delay broadcast over N,C)
#define W         64                        // columns per block

__device__ __forceinline__ uint32_t rotl32(uint32_t x, int n) {
    return (x << n) | (x >> (32 - n));
}

// JAX threefry2x32-20, jax_threefry_partitionable=True (modern default):
// per-element counter (0, j), output = x0 ^ x1. Key = PRNGKey(42) = (0,42).
// Verified passing in rounds 2-3 — DO NOT TOUCH.
__device__ __forceinline__ uint32_t jax_bits_partitionable(uint32_t j) {
    uint32_t x0 = 0u, x1 = j;
    const uint32_t ks0 = 0u;
    const uint32_t ks1 = 42u;
    const uint32_t ks2 = 0x1BD11BDAu ^ 0u ^ 42u;
    x0 += ks0; x1 += ks1;
#define RND(r) { x0 += x1; x1 = rotl32(x1, r); x1 ^= x0; }
    RND(13) RND(15) RND(26) RND(6)
    x0 += ks1; x1 += ks2 + 1u;
    RND(17) RND(29) RND(16) RND(24)
    x0 += ks2; x1 += ks0 + 2u;
    RND(13) RND(15) RND(26) RND(6)
    x0 += ks0; x1 += ks1 + 3u;
    RND(17) RND(29) RND(16) RND(24)
    x0 += ks1; x1 += ks2 + 4u;
    RND(13) RND(15) RND(26) RND(6)
    x0 += ks2; x1 += ks0 + 5u;
#undef RND
    return x0 ^ x1;
}

__device__ __forceinline__ float sigmoidf_(float x) {
    return 1.0f / (1.0f + expf(-x));   // same formula as the passing rounds
}

__device__ __forceinline__ uint32_t bf16rne(float x) {
    uint32_t u = __float_as_uint(x);               // sigma: finite, non-NaN
    return (u + 0x7FFFu + ((u >> 16) & 1u)) >> 16; // round-to-nearest-even
}

// Fused kernel, one block per 64 columns:
//  phase 1 : coalesced float4 load, sigma once, argmax folded into the load
//            loop (fp32 regs -> shift indices identical to round 3), bf16(RNE)
//            sigma tile -> LDS (32 KiB => 4 blocks/CU)
//  phase 1b: 16-candidate/column reduce with (v>bm)||(v==bm&&i<bi) tie-break
//            (exact first-max), threefry bernoulli round + spike clamp -> d[c]
//  phase 2 : out[r,c] = tile[(r-d_c)&255][c] ; conflict-free u16 LDS reads
//            (lane pairs broadcast one dword), 256B/wave coalesced stores
extern "C" __global__ __launch_bounds__(256, 4)
void td_fused(const float* __restrict__ in, const float* __restrict__ delay,
              float* __restrict__ out) {
    __shared__ unsigned short tile16[TT * W];      // 32 KiB bf16 sigma tile
    __shared__ float          redv[16 * W];        // 4 KiB per-rowset max
    __shared__ unsigned char  redi[16 * W];        // 1 KiB per-rowset argmax
    __shared__ int            dint[W];

    const int c0  = blockIdx.x * W;
    const int tid = threadIdx.x;
    const int f   = tid & 15;                      // float4 slot (4 columns)
    const int r0  = tid >> 4;                      // row-set 0..15

    // ---- phase 1: load + sigmoid + register argmax -> bf16 LDS tile ----
    const float4* in4 = (const float4*)in;
    float bm0 = -1.0f, bm1 = -1.0f, bm2 = -1.0f, bm3 = -1.0f;
    int   bi0 = 0, bi1 = 0, bi2 = 0, bi3 = 0;
#pragma unroll 8
    for (int k = 0; k < 16; ++k) {
        const int t = r0 + (k << 4);               // increasing t per thread
        float4 v = in4[(size_t)t * CS4 + (c0 >> 2) + f];
        float s0 = sigmoidf_(v.x);
        float s1 = sigmoidf_(v.y);
        float s2 = sigmoidf_(v.z);
        float s3 = sigmoidf_(v.w);
        if (s0 > bm0) { bm0 = s0; bi0 = t; }       // strict > keeps first t
        if (s1 > bm1) { bm1 = s1; bi1 = t; }
        if (s2 > bm2) { bm2 = s2; bi2 = t; }
        if (s3 > bm3) { bm3 = s3; bi3 = t; }
        uint2 p;
        p.x = bf16rne(s0) | (bf16rne(s1) << 16);
        p.y = bf16rne(s2) | (bf16rne(s3) << 16);
        *(uint2*)&tile16[t * W + (f << 2)] = p;    // 8B aligned ds_write_b64
    }
    *(float4*)&redv[r0 * W + (f << 2)] = make_float4(bm0, bm1, bm2, bm3);
    *(uint32_t*)&redi[r0 * W + (f << 2)] =
        (uint32_t)bi0 | ((uint32_t)bi1 << 8) |
        ((uint32_t)bi2 << 16) | ((uint32_t)bi3 << 24);
    __syncthreads();

    // ---- phase 1b: cross-rowset reduce + threefry round + clamp ----
    if (tid < W) {
        float bm = redv[tid];
        int   bi = redi[tid];
#pragma unroll
        for (int r = 1; r < 16; ++r) {
            float v = redv[r * W + tid];
            int   i = redi[r * W + tid];
            if (v > bm || (v == bm && i < bi)) { bm = v; bi = i; }  // first-max
        }
        const int jj = c0 + tid;
        float dl = delay[jj & DMASK];              // broadcast over (N,C)
        float df = floorf(dl);
        float fr = dl - df;                        // exact in fp32
        uint32_t bits = jax_bits_partitionable((uint32_t)jj);
        float u = __uint_as_float((bits >> 9) | 0x3f800000u) - 1.0f;  // [0,1)
        float dr = (u < fr) ? df + 1.0f : df;      // bernoulli round
        dr = fminf(dr, (float)(TT - 1 - bi));      // spike-no-wrap clamp
        dint[tid] = (int)dr;
    }
    __syncthreads();

    // ---- phase 2: rotate + coalesced write ----
    const int c = tid & 63;
    const int w = tid >> 6;                        // wave id 0..3
    const int d = dint[c];
    int s = (w - d) & (TT - 1);
    const size_t obase = (size_t)w * COLS + c0 + c;
#pragma unroll
    for (int k = 0; k < 64; ++k) {                 // row r = 4k + w
        unsigned short h = tile16[s * W + c];
        out[obase + (size_t)(k * 4) * COLS] = __uint_as_float((uint32_t)h << 16);
        s = (s + 4) & (TT - 1);
    }
}

extern "C" void kernel_launch(void* const* d_in, const int* in_sizes, int n_in,
                              void* d_out, int out_size, void* d_ws, size_t ws_size,
                              hipStream_t stream) {
    const float* in    = (const float*)d_in[0];   // (T,N,C,Do,Di) f32
    const float* delay = (const float*)d_in[1];   // (Do,Di) f32
    float* out = (float*)d_out;

    hipLaunchKernelGGL(td_fused, dim3(COLS / W), dim3(256), 0, stream,
                       in, delay, out);
}